// Round 12
// baseline (257.450 us; speedup 1.0000x reference)
//
#include <hip/hip_runtime.h>

#define B_SZ 4
#define SEQ  4096
#define DM   1024
#define DSTATE 16
#define ROWS (B_SZ*SEQ)   // 16384

typedef unsigned short u16;
typedef __attribute__((ext_vector_type(8))) short   s16x8;   // 8 bf16 (4 VGPRs)
typedef __attribute__((ext_vector_type(4))) float   f32x4;
typedef __attribute__((ext_vector_type(4))) u16     u16x4;

__device__ inline float bf2f(u16 u) {
    unsigned v = ((unsigned)u) << 16;
    float f; __builtin_memcpy(&f, &v, 4); return f;
}
__device__ inline u16 f2bf(float f) {
    unsigned u; __builtin_memcpy(&u, &f, 4);
    return (u16)((u + 0x7FFFu + ((u >> 16) & 1u)) >> 16);   // RNE
}
__device__ inline f32x4 mfma16(s16x8 a, s16x8 b, f32x4 c) {
    return __builtin_amdgcn_mfma_f32_16x16x32_bf16(a, b, c, 0, 0, 0);
}
// async global->LDS, 16B per lane, dest = wave-uniform base + lane*16
__device__ inline void gl_lds16(const u16* g, u16* l) {
    __builtin_amdgcn_global_load_lds(
        (const __attribute__((address_space(1))) unsigned int*)g,
        (__attribute__((address_space(3))) unsigned int*)l, 16, 0, 0);
}

#define WAITV(N) asm volatile("s_waitcnt vmcnt(" #N ")" ::: "memory")

// ---------------------------------------------------------------------------
// K0b: weight conversions in one launch.
// ---------------------------------------------------------------------------
__global__ __launch_bounds__(256) void k_cvt_w(
    const float* __restrict__ gw, const float* __restrict__ Bw,
    const float* __restrict__ Cw, u16* __restrict__ gwb,
    u16* __restrict__ bwh, u16* __restrict__ bwl,
    u16* __restrict__ cwh, u16* __restrict__ cwl)
{
    int blk = blockIdx.x;
    if (blk < 1024) {
        int i = blk * 256 + threadIdx.x;
        f32x4 v = ((const f32x4*)gw)[i];
        u16x4 o;
#pragma unroll
        for (int c = 0; c < 4; c++) o[c] = f2bf(v[c]);
        ((u16x4*)gwb)[i] = o;
    } else {
        int isC = (blk >= 1040);
        const float* src = isC ? Cw : Bw;
        u16* dh = isC ? cwh : bwh;
        u16* dl = isC ? cwl : bwl;
        int i = (blk - (isC ? 1040 : 1024)) * 256 + threadIdx.x;
        f32x4 v = ((const f32x4*)src)[i];
        u16x4 h, l;
#pragma unroll
        for (int c = 0; c < 4; c++) {
            h[c] = f2bf(v[c]);
            l[c] = f2bf(v[c] - bf2f(h[c]));
        }
        ((u16x4*)dh)[i] = h;
        ((u16x4*)dl)[i] = l;
    }
}

// ---------------------------------------------------------------------------
// K1: Bx/Cx = x @ B_w^T, x @ C_w^T, full-K, 3-pass split-bf16 MFMA.
// R12: K-split (R8, null result) reverted -> no partial slabs, no reduce.
// All 4 weight arrays staged for FULL K in 128 KB LDS once per block
// (R9's line-touch fix, extended).  Grid = ROWS/64 = 256 blocks (1/CU),
// 4 waves; wave w owns rows blk*64 + w*16 end-to-end -> writes final Bx/Cx.
// x prefetch double-buffered across K-quarters (named reg groups, static
// indexing).  Single 32-iter MFMA chain = R7's accumulation order.
// ---------------------------------------------------------------------------
__global__ __launch_bounds__(256) void k_bxcx(
    const float* __restrict__ x,
    const u16* __restrict__ bwh, const u16* __restrict__ bwl,
    const u16* __restrict__ cwh, const u16* __restrict__ cwl,
    u16* __restrict__ xh,
    float* __restrict__ Bx, float* __restrict__ Cx)
{
    __shared__ u16 sW[4][16][DM];   // 128 KB; phys chunk p holds src chunk p^(row&7)
    int tid = threadIdx.x;
    int wv = tid >> 6, lane = tid & 63;
    int lo = lane & 15, hi = lane >> 4;
    int m0 = blockIdx.x * 64 + wv * 16;

    // stage: wave wv -> array wv (32 KB each, 32 issues/lane, linear LDS dest)
    {
        const u16* wsrc = (wv == 0) ? bwh : (wv == 1) ? bwl : (wv == 2) ? cwh : cwl;
#pragma unroll
        for (int i = 0; i < 32; i++) {
            int row = i >> 1, hh = i & 1;
            int p = hh * 64 + lane;         // physical 16B chunk in row
            int c = p ^ (row & 7);          // source chunk (involution)
            gl_lds16(wsrc + (size_t)row * DM + c * 8, &sW[wv][row][hh * 512]);
        }
    }

    const float* xbase = x + (size_t)(m0 + lo) * DM + hi * 8;
    u16* xhbase = xh + (size_t)(m0 + lo) * DM + hi * 8;

    WAITV(0);
    __builtin_amdgcn_s_barrier();

    f32x4 accB = {}, accC = {};

    // prefetch one K-quarter (8 iters = 16 f32x4) into named regs
#define PFQ(Q, R0, R1)                                                        \
    do {                                                                      \
        _Pragma("unroll")                                                     \
        for (int j = 0; j < 8; j++) {                                         \
            R0[j] = *(const f32x4*)(xbase + ((Q) * 8 + j) * 32);              \
            R1[j] = *(const f32x4*)(xbase + ((Q) * 8 + j) * 32 + 4);          \
        }                                                                     \
    } while (0)

#define CQ(Q, R0, R1)                                                         \
    do {                                                                      \
        _Pragma("unroll")                                                     \
        for (int j = 0; j < 8; j++) {                                         \
            int it = (Q) * 8 + j;                                             \
            f32x4 v0 = R0[j], v1 = R1[j];                                     \
            s16x8 ah, al;                                                     \
            _Pragma("unroll")                                                 \
            for (int c2 = 0; c2 < 4; c2++) {                                  \
                u16 h0 = f2bf(v0[c2]);                                        \
                ah[c2]     = (short)h0;                                       \
                al[c2]     = (short)f2bf(v0[c2] - bf2f(h0));                  \
                u16 h1 = f2bf(v1[c2]);                                        \
                ah[4 + c2] = (short)h1;                                       \
                al[4 + c2] = (short)f2bf(v1[c2] - bf2f(h1));                  \
            }                                                                 \
            *(s16x8*)(xhbase + it * 32) = ah;                                 \
            int pc = (it * 4 + hi) ^ (lo & 7);                                \
            s16x8 bh = *(const s16x8*)&sW[0][lo][pc * 8];                     \
            s16x8 bl = *(const s16x8*)&sW[1][lo][pc * 8];                     \
            s16x8 ch = *(const s16x8*)&sW[2][lo][pc * 8];                     \
            s16x8 cl = *(const s16x8*)&sW[3][lo][pc * 8];                     \
            accB = mfma16(ah, bh, accB);                                      \
            accB = mfma16(al, bh, accB);                                      \
            accB = mfma16(ah, bl, accB);                                      \
            accC = mfma16(ah, ch, accC);                                      \
            accC = mfma16(al, ch, accC);                                      \
            accC = mfma16(ah, cl, accC);                                      \
        }                                                                     \
    } while (0)

    f32x4 vA0[8], vA1[8], vB0[8], vB1[8];
    PFQ(0, vA0, vA1);
    PFQ(1, vB0, vB1);
    CQ(0, vA0, vA1);
    PFQ(2, vA0, vA1);
    CQ(1, vB0, vB1);
    PFQ(3, vB0, vB1);
    CQ(2, vA0, vA1);
    CQ(3, vB0, vB1);
#undef PFQ
#undef CQ

#pragma unroll
    for (int r = 0; r < 4; r++) {
        int m = m0 + hi * 4 + r;
        Bx[(size_t)m * DSTATE + lo] = accB[r];
        Cx[(size_t)m * DSTATE + lo] = accC[r];
    }
}

// ---------------------------------------------------------------------------
// K2: gate = sigmoid(x @ gate_w^T + gate_b), fp32 out (into d_out).
// 256x256 tile, BK=64, counted vmcnt + raw s_barrier + low-pressure MFMA
// cadence (R10-verified).  Grid exactly 256 blocks = 1/CU (no extra blocks:
// R11's fused reduce caused a second CU-round and +21MB fetch -> reverted).
// ---------------------------------------------------------------------------
#define GBM 256
#define GBN 256
#define GBK 64
#define NKT (DM / GBK)   // 16

__global__ __launch_bounds__(512) void k_gate(
    const u16* __restrict__ xh, const u16* __restrict__ gwb,
    const float* __restrict__ gb, float* __restrict__ gate)
{
    __shared__ u16 sA[2][GBM * GBK];   // 2 x 32 KB
    __shared__ u16 sB[2][GBN * GBK];   // 2 x 32 KB  (128 KB total, 1 blk/CU)
    int tid = threadIdx.x;
    int wv = tid >> 6, lane = tid & 63;
    int lo = lane & 15, hi = lane >> 4;
    int wm = wv >> 2, wn = wv & 3;     // 2 x 4 wave grid
    int m0 = blockIdx.x * GBM;
    int n0 = blockIdx.y * GBN;

    int r_in = lane >> 3;      // row within 8-row wave staging group
    int p    = lane & 7;       // physical 16B chunk slot in LDS row
    int c    = p ^ r_in;       // swizzled source chunk (row&7 == r_in)

    // stage one 256x64 tile-pair (A+B) into buf: 4 issues x 64 rows each
    auto stage = [&](int buf, int k0) {
#pragma unroll
        for (int q = 0; q < 4; q++) {
            int r = q * 64 + wv * 8 + r_in;
            size_t goff = (size_t)r * DM + k0 + c * 8;
            gl_lds16(xh  + (size_t)m0 * DM + goff, &sA[buf][(q * 64 + wv * 8) * GBK]);
            gl_lds16(gwb + (size_t)n0 * DM + goff, &sB[buf][(q * 64 + wv * 8) * GBK]);
        }
    };

    f32x4 acc[8][4] = {};

    stage(0, 0);                       // 8 loads in flight

    for (int ks = 0; ks < NKT; ks++) {
        int buf = ks & 1;
        if (ks + 1 < NKT) {
            stage(buf ^ 1, (ks + 1) * GBK);   // +8 -> 16 in flight
            WAITV(8);                          // tile-ks's 8 complete
        } else {
            WAITV(0);
        }
        __builtin_amdgcn_s_barrier();          // all waves' tile-ks writes visible
#pragma unroll
        for (int kk = 0; kk < 2; kk++) {
            s16x8 bfr[4];
#pragma unroll
            for (int j = 0; j < 4; j++) {
                int rb = wn * 64 + j * 16 + lo;
                int pc = (kk * 4 + hi) ^ (rb & 7);
                bfr[j] = *(const s16x8*)&sB[buf][rb * GBK + pc * 8];
            }
            int ra0 = wm * 128 + lo;
            int pc0 = (kk * 4 + hi) ^ (ra0 & 7);
            s16x8 a_cur = *(const s16x8*)&sA[buf][ra0 * GBK + pc0 * 8];
            __builtin_amdgcn_s_setprio(1);
#pragma unroll
            for (int i = 0; i < 8; i++) {
                s16x8 a_nxt;
                if (i < 7) {
                    int ra = wm * 128 + (i + 1) * 16 + lo;
                    int pc = (kk * 4 + hi) ^ (ra & 7);
                    a_nxt = *(const s16x8*)&sA[buf][ra * GBK + pc * 8];
                }
#pragma unroll
                for (int j = 0; j < 4; j++)
                    acc[i][j] = mfma16(a_cur, bfr[j], acc[i][j]);
                if (i < 7) a_cur = a_nxt;
            }
            __builtin_amdgcn_s_setprio(0);
        }
        __builtin_amdgcn_s_barrier();          // protect buf reuse next iter
    }

#pragma unroll
    for (int i = 0; i < 8; i++)
#pragma unroll
        for (int r = 0; r < 4; r++) {
            int m = m0 + wm * 128 + i * 16 + hi * 4 + r;
#pragma unroll
            for (int j = 0; j < 4; j++) {
                int n = n0 + wn * 64 + j * 16 + lo;
                float v = acc[i][j][r] + gb[n];
                gate[(size_t)m * DM + n] = 1.0f / (1.0f + __expf(-v));
            }
        }
}

// ---------------------------------------------------------------------------
// K3: windowed scan, register-prefetch bodies, NO LDS (R11-verified).
// Bx/Cx read via block-uniform addresses -> s_load broadcast.
// LOOKBACK 16: A <= e^-1 -> truncation ~1.2e-7 relative.
// ---------------------------------------------------------------------------
#define CHUNK_L 64
#define LOOKBACK 16

__global__ __launch_bounds__(256) void k_scan(
    const float* __restrict__ x, const float* __restrict__ A_log,
    const float* __restrict__ Bx, const float* __restrict__ Cx,
    const float* __restrict__ Dvec, float* gate_out)
{
    int d = blockIdx.x * 256 + threadIdx.x;   // 0..1023
    int b = blockIdx.z;
    int t0 = blockIdx.y * CHUNK_L;
    int tstart = t0 - LOOKBACK; if (tstart < 0) tstart = 0;
    int lb = t0 - tstart;                     // 0 or 16
    int T  = lb + CHUNK_L;                    // 64 or 80
    int NB = T >> 3;                          // 8 or 10 bodies (even)

    float A[DSTATE], h[DSTATE];
    const f32x4* ga = (const f32x4*)(A_log + (size_t)d * DSTATE);
#pragma unroll
    for (int q = 0; q < 4; q++) {
        f32x4 av = ga[q];
#pragma unroll
        for (int c = 0; c < 4; c++) {
            A[q * 4 + c] = expf(av[c]);
            h[q * 4 + c] = 0.0f;
        }
    }
    float Dd = Dvec[d];

    const float* xp = x + ((size_t)b * SEQ + tstart) * DM + d;
    float* gp = gate_out + ((size_t)b * SEQ + t0) * DM + d;
    // block-uniform row bases (scalarizable)
    const f32x4* bA = (const f32x4*)(Bx + ((size_t)b * SEQ + tstart) * DSTATE);
    const f32x4* cA = (const f32x4*)(Cx + ((size_t)b * SEQ + tstart) * DSTATE);

    auto pf = [&](int bd, float (&xr)[8], float (&gr)[8]) {
        int base = bd * 8;
#pragma unroll
        for (int q = 0; q < 8; q++) xr[q] = xp[(size_t)(base + q) * DM];
        if (base >= lb) {
#pragma unroll
            for (int q = 0; q < 8; q++) gr[q] = gp[(size_t)(base + q - lb) * DM];
        }
    };

    auto body = [&](int bd, float (&xr)[8], float (&gr)[8]) {
        int base = bd * 8;
        if (base >= lb) {
            float* go = gp + (size_t)(base - lb) * DM;
#pragma unroll
            for (int q = 0; q < 8; q++) {
                int idx = base + q;
                float xv = xr[q], gv = gr[q];
                f32x4 vb0 = bA[idx * 4 + 0], vb1 = bA[idx * 4 + 1];
                f32x4 vb2 = bA[idx * 4 + 2], vb3 = bA[idx * 4 + 3];
                f32x4 vc0 = cA[idx * 4 + 0], vc1 = cA[idx * 4 + 1];
                f32x4 vc2 = cA[idx * 4 + 2], vc3 = cA[idx * 4 + 3];
                float y0 = 0.f, y1 = 0.f, y2 = 0.f, y3 = 0.f;
#pragma unroll
                for (int c = 0; c < 4; c++) {
                    h[c]      = h[c]      * A[c]      + vb0[c] * xv;  y0 += h[c]      * vc0[c];
                    h[4 + c]  = h[4 + c]  * A[4 + c]  + vb1[c] * xv;  y1 += h[4 + c]  * vc1[c];
                    h[8 + c]  = h[8 + c]  * A[8 + c]  + vb2[c] * xv;  y2 += h[8 + c]  * vc2[c];
                    h[12 + c] = h[12 + c] * A[12 + c] + vb3[c] * xv;  y3 += h[12 + c] * vc3[c];
                }
                float yv = ((y0 + y1) + (y2 + y3)) + Dd * xv;
                go[(size_t)q * DM] = gv * yv + (1.0f - gv) * xv;
            }
        } else {
#pragma unroll
            for (int q = 0; q < 8; q++) {
                int idx = base + q;
                float xv = xr[q];
                f32x4 vb0 = bA[idx * 4 + 0], vb1 = bA[idx * 4 + 1];
                f32x4 vb2 = bA[idx * 4 + 2], vb3 = bA[idx * 4 + 3];
#pragma unroll
                for (int c = 0; c < 4; c++) {
                    h[c]      = h[c]      * A[c]      + vb0[c] * xv;
                    h[4 + c]  = h[4 + c]  * A[4 + c]  + vb1[c] * xv;
                    h[8 + c]  = h[8 + c]  * A[8 + c]  + vb2[c] * xv;
                    h[12 + c] = h[12 + c] * A[12 + c] + vb3[c] * xv;
                }
            }
        }
    };

    float xA[8], gA[8], xB[8], gB8[8];
    pf(0, xA, gA);
    for (int bd = 0; bd < NB; bd += 2) {
        pf(bd + 1, xB, gB8);          // issue next body's loads before compute
        body(bd, xA, gA);
        if (bd + 2 < NB) pf(bd + 2, xA, gA);
        body(bd + 1, xB, gB8);
    }
}

// ---------------------------------------------------------------------------
// K4: LayerNorm over last dim (1024), fp32, IN PLACE on d_out.
// ---------------------------------------------------------------------------
__global__ __launch_bounds__(256) void k_ln(
    float* data, const float* __restrict__ gamma, const float* __restrict__ beta)
{
    int wv = threadIdx.x >> 6, lane = threadIdx.x & 63;
    int row = blockIdx.x * 4 + wv;
    f32x4* rp = (f32x4*)(data + (size_t)row * DM);
    f32x4 v[4];
#pragma unroll
    for (int j = 0; j < 4; j++) v[j] = rp[lane + 64 * j];
    float s = 0.0f, s2 = 0.0f;
#pragma unroll
    for (int j = 0; j < 4; j++)
#pragma unroll
        for (int c = 0; c < 4; c++) { float t = v[j][c]; s += t; s2 += t * t; }
#pragma unroll
    for (int off = 32; off > 0; off >>= 1) {
        s  += __shfl_down(s,  off);
        s2 += __shfl_down(s2, off);
    }
    s = __shfl(s, 0); s2 = __shfl(s2, 0);
    float mu  = s  * (1.0f / DM);
    float var = s2 * (1.0f / DM) - mu * mu;
    float rs  = rsqrtf(var + 1e-5f);
#pragma unroll
    for (int j = 0; j < 4; j++) {
        int c0 = (lane + 64 * j) * 4;
        f32x4 o;
#pragma unroll
        for (int c = 0; c < 4; c++)
            o[c] = (v[j][c] - mu) * rs * gamma[c0 + c] + beta[c0 + c];
        rp[lane + 64 * j] = o;
    }
}

// ---------------------------------------------------------------------------
extern "C" void kernel_launch(void* const* d_in, const int* in_sizes, int n_in,
                              void* d_out, int out_size, void* d_ws, size_t ws_size,
                              hipStream_t stream)
{
    const float* x     = (const float*)d_in[0];
    const float* A_log = (const float*)d_in[1];
    const float* Bw    = (const float*)d_in[2];
    const float* Cw    = (const float*)d_in[3];
    const float* Dv    = (const float*)d_in[4];
    const float* gw    = (const float*)d_in[5];
    const float* gb    = (const float*)d_in[6];
    const float* gam   = (const float*)d_in[7];
    const float* bet   = (const float*)d_in[8];
    float* out = (float*)d_out;   // reused: gate (fp32) -> out_pre -> final

    char* ws = (char*)d_ws;
    u16*   xh  = (u16*)  ws;                             // 32 MB
    float* Bx  = (float*)(ws + (32u << 20));             // 1 MB
    float* Cx  = (float*)(ws + (33u << 20));             // 1 MB
    u16*   gwb = (u16*)  (ws + (64u << 20));             // 2 MB
    u16*   bwh = (u16*)  (ws + (66u << 20));             // 32 KB
    u16*   bwl = (u16*)  (ws + (66u << 20) + (32u << 10));
    u16*   cwh = (u16*)  (ws + (66u << 20) + (64u << 10));
    u16*   cwl = (u16*)  (ws + (66u << 20) + (96u << 10));

    k_cvt_w<<<1056, 256, 0, stream>>>(gw, Bw, Cw, gwb, bwh, bwl, cwh, cwl);
    k_bxcx<<<ROWS / 64, 256, 0, stream>>>(x, bwh, bwl, cwh, cwl, xh, Bx, Cx);
    k_gate<<<dim3(ROWS / GBM, DM / GBN), 512, 0, stream>>>(xh, gwb, gb, out);
    k_scan<<<dim3(DM / 256, SEQ / CHUNK_L, B_SZ), 256, 0, stream>>>(
        x, A_log, Bx, Cx, Dv, out);
    k_ln<<<ROWS / 4, 256, 0, stream>>>(out, gam, bet);
}

// Round 13
// 242.846 us; speedup vs baseline: 1.0601x; 1.0601x over previous
//
#include <hip/hip_runtime.h>

#define B_SZ 4
#define SEQ  4096
#define DM   1024
#define DSTATE 16
#define ROWS (B_SZ*SEQ)   // 16384
#define XKS 4             // K-split factor for k_bxcx
#define XKL (DM / XKS)    // 256
#define SLAB_V4 (ROWS * DSTATE / 4)   // 65536 f32x4 per slab

typedef unsigned short u16;
typedef __attribute__((ext_vector_type(8))) short   s16x8;   // 8 bf16 (4 VGPRs)
typedef __attribute__((ext_vector_type(4))) float   f32x4;
typedef __attribute__((ext_vector_type(4))) u16     u16x4;

__device__ inline float bf2f(u16 u) {
    unsigned v = ((unsigned)u) << 16;
    float f; __builtin_memcpy(&f, &v, 4); return f;
}
__device__ inline u16 f2bf(float f) {
    unsigned u; __builtin_memcpy(&u, &f, 4);
    return (u16)((u + 0x7FFFu + ((u >> 16) & 1u)) >> 16);   // RNE
}
__device__ inline f32x4 mfma16(s16x8 a, s16x8 b, f32x4 c) {
    return __builtin_amdgcn_mfma_f32_16x16x32_bf16(a, b, c, 0, 0, 0);
}
// async global->LDS, 16B per lane, dest = wave-uniform base + lane*16
__device__ inline void gl_lds16(const u16* g, u16* l) {
    __builtin_amdgcn_global_load_lds(
        (const __attribute__((address_space(1))) unsigned int*)g,
        (__attribute__((address_space(3))) unsigned int*)l, 16, 0, 0);
}

#define WAITV(N) asm volatile("s_waitcnt vmcnt(" #N ")" ::: "memory")

// ---------------------------------------------------------------------------
// K0b: weight conversions in one launch.
// ---------------------------------------------------------------------------
__global__ __launch_bounds__(256) void k_cvt_w(
    const float* __restrict__ gw, const float* __restrict__ Bw,
    const float* __restrict__ Cw, u16* __restrict__ gwb,
    u16* __restrict__ bwh, u16* __restrict__ bwl,
    u16* __restrict__ cwh, u16* __restrict__ cwl)
{
    int blk = blockIdx.x;
    if (blk < 1024) {
        int i = blk * 256 + threadIdx.x;
        f32x4 v = ((const f32x4*)gw)[i];
        u16x4 o;
#pragma unroll
        for (int c = 0; c < 4; c++) o[c] = f2bf(v[c]);
        ((u16x4*)gwb)[i] = o;
    } else {
        int isC = (blk >= 1040);
        const float* src = isC ? Cw : Bw;
        u16* dh = isC ? cwh : bwh;
        u16* dl = isC ? cwl : bwl;
        int i = (blk - (isC ? 1040 : 1024)) * 256 + threadIdx.x;
        f32x4 v = ((const f32x4*)src)[i];
        u16x4 h, l;
#pragma unroll
        for (int c = 0; c < 4; c++) {
            h[c] = f2bf(v[c]);
            l[c] = f2bf(v[c] - bf2f(h[c]));
        }
        ((u16x4*)dh)[i] = h;
        ((u16x4*)dl)[i] = l;
    }
}

// ---------------------------------------------------------------------------
// K1: partial Bx/Cx over a K-quarter, 3-pass split-bf16 MFMA (fp32-grade).
// R9-verified exact source: weights staged to LDS once per block (line-touch
// fix), deep x-prefetch, K-split grid (ROWS/64, XKS), partial slabs out.
// ---------------------------------------------------------------------------
__global__ __launch_bounds__(256) void k_bxcx(
    const float* __restrict__ x,
    const u16* __restrict__ bwh, const u16* __restrict__ bwl,
    const u16* __restrict__ cwh, const u16* __restrict__ cwl,
    u16* __restrict__ xh,
    float* __restrict__ BxP, float* __restrict__ CxP)
{
    __shared__ u16 sW[4][16][XKL];   // 32 KB; phys chunk p holds src chunk p^(row&7)
    int tid = threadIdx.x;
    int wv = tid >> 6, lane = tid & 63;
    int lo = lane & 15, hi = lane >> 4;
    int m0 = blockIdx.x * 64 + wv * 16;
    int kq = blockIdx.y;
    int kbase = kq * XKL;

    // stage: wave wv -> array wv; instr i covers rows 2i,2i+1 (1KB linear LDS)
    {
        const u16* wsrc = (wv == 0) ? bwh : (wv == 1) ? bwl : (wv == 2) ? cwh : cwl;
        int rhalf = lane >> 5;          // row within the instr's 2-row pair
        int p     = lane & 31;          // physical 16B chunk slot
#pragma unroll
        for (int i = 0; i < 8; i++) {
            int row = i * 2 + rhalf;
            int c   = p ^ (row & 7);    // source chunk (involution)
            gl_lds16(wsrc + (size_t)row * DM + kbase + c * 8, &sW[wv][i * 2][0]);
        }
    }

    const float* xbase = x + (size_t)(m0 + lo) * DM + kbase + hi * 8;
    u16* xhbase = xh + (size_t)(m0 + lo) * DM + kbase + hi * 8;

    WAITV(0);                           // weights staged (cheap, once per block)
    __builtin_amdgcn_s_barrier();

    // deep-prefetch all 8 iters' x (16 loads in flight; compiler waits per-use)
    f32x4 v0r[8], v1r[8];
#pragma unroll
    for (int it = 0; it < 8; it++) {
        v0r[it] = *(const f32x4*)(xbase + it * 32);
        v1r[it] = *(const f32x4*)(xbase + it * 32 + 4);
    }

    f32x4 accB = {}, accC = {};
#pragma unroll
    for (int it = 0; it < 8; it++) {
        f32x4 v0 = v0r[it], v1 = v1r[it];
        s16x8 ah, al;
#pragma unroll
        for (int c2 = 0; c2 < 4; c2++) {
            u16 h0 = f2bf(v0[c2]);
            ah[c2]     = (short)h0;
            al[c2]     = (short)f2bf(v0[c2] - bf2f(h0));
            u16 h1 = f2bf(v1[c2]);
            ah[4 + c2] = (short)h1;
            al[4 + c2] = (short)f2bf(v1[c2] - bf2f(h1));
        }
        *(s16x8*)(xhbase + it * 32) = ah;       // side-product: xh for k_gate
        int pc = (it * 4 + hi) ^ (lo & 7);
        s16x8 bh = *(const s16x8*)&sW[0][lo][pc * 8];
        s16x8 bl = *(const s16x8*)&sW[1][lo][pc * 8];
        s16x8 ch = *(const s16x8*)&sW[2][lo][pc * 8];
        s16x8 cl = *(const s16x8*)&sW[3][lo][pc * 8];
        accB = mfma16(ah, bh, accB);
        accB = mfma16(al, bh, accB);
        accB = mfma16(ah, bl, accB);
        accC = mfma16(ah, ch, accC);
        accC = mfma16(al, ch, accC);
        accC = mfma16(ah, cl, accC);
    }

    float* bOut = BxP + (size_t)kq * ROWS * DSTATE;
    float* cOut = CxP + (size_t)kq * ROWS * DSTATE;
#pragma unroll
    for (int r = 0; r < 4; r++) {
        int m = m0 + hi * 4 + r;
        bOut[(size_t)m * DSTATE + lo] = accB[r];
        cOut[(size_t)m * DSTATE + lo] = accC[r];
    }
}

// ---------------------------------------------------------------------------
// K1b: reduce the 4 partial slabs -> single Bx/Cx.  Standalone (decoupled
// from k_gate: R11's fused variant caused a second CU-round + 21MB fetch).
// Sum order ((s0+s1)+s2)+s3 == R9's in-scan order -> bit-identical values.
// 10 MB traffic, ~4 us.
// ---------------------------------------------------------------------------
__global__ __launch_bounds__(256) void k_red(
    const float* __restrict__ BxP, const float* __restrict__ CxP,
    float* __restrict__ BxR, float* __restrict__ CxR)
{
    int i = blockIdx.x * 256 + threadIdx.x;          // 0..65535
    const f32x4* b = (const f32x4*)BxP;
    const f32x4* c = (const f32x4*)CxP;
    f32x4 vb = ((b[i] + b[i + SLAB_V4]) + b[i + 2 * SLAB_V4]) + b[i + 3 * SLAB_V4];
    f32x4 vc = ((c[i] + c[i + SLAB_V4]) + c[i + 2 * SLAB_V4]) + c[i + 3 * SLAB_V4];
    ((f32x4*)BxR)[i] = vb;
    ((f32x4*)CxR)[i] = vc;
}

// ---------------------------------------------------------------------------
// K2: gate = sigmoid(x @ gate_w^T + gate_b), fp32 out (into d_out).
// 256x256 tile, BK=64, counted vmcnt + raw s_barrier + low-pressure MFMA
// cadence (R10/R12-verified, ~54us in two modules).  Grid exactly 256 blocks.
// ---------------------------------------------------------------------------
#define GBM 256
#define GBN 256
#define GBK 64
#define NKT (DM / GBK)   // 16

__global__ __launch_bounds__(512) void k_gate(
    const u16* __restrict__ xh, const u16* __restrict__ gwb,
    const float* __restrict__ gb, float* __restrict__ gate)
{
    __shared__ u16 sA[2][GBM * GBK];   // 2 x 32 KB
    __shared__ u16 sB[2][GBN * GBK];   // 2 x 32 KB  (128 KB total, 1 blk/CU)
    int tid = threadIdx.x;
    int wv = tid >> 6, lane = tid & 63;
    int lo = lane & 15, hi = lane >> 4;
    int wm = wv >> 2, wn = wv & 3;     // 2 x 4 wave grid
    int m0 = blockIdx.x * GBM;
    int n0 = blockIdx.y * GBN;

    int r_in = lane >> 3;      // row within 8-row wave staging group
    int p    = lane & 7;       // physical 16B chunk slot in LDS row
    int c    = p ^ r_in;       // swizzled source chunk (row&7 == r_in)

    // stage one 256x64 tile-pair (A+B) into buf: 4 issues x 64 rows each
    auto stage = [&](int buf, int k0) {
#pragma unroll
        for (int q = 0; q < 4; q++) {
            int r = q * 64 + wv * 8 + r_in;
            size_t goff = (size_t)r * DM + k0 + c * 8;
            gl_lds16(xh  + (size_t)m0 * DM + goff, &sA[buf][(q * 64 + wv * 8) * GBK]);
            gl_lds16(gwb + (size_t)n0 * DM + goff, &sB[buf][(q * 64 + wv * 8) * GBK]);
        }
    };

    f32x4 acc[8][4] = {};

    stage(0, 0);                       // 8 loads in flight

    for (int ks = 0; ks < NKT; ks++) {
        int buf = ks & 1;
        if (ks + 1 < NKT) {
            stage(buf ^ 1, (ks + 1) * GBK);   // +8 -> 16 in flight
            WAITV(8);                          // tile-ks's 8 complete
        } else {
            WAITV(0);
        }
        __builtin_amdgcn_s_barrier();          // all waves' tile-ks writes visible
#pragma unroll
        for (int kk = 0; kk < 2; kk++) {
            s16x8 bfr[4];
#pragma unroll
            for (int j = 0; j < 4; j++) {
                int rb = wn * 64 + j * 16 + lo;
                int pc = (kk * 4 + hi) ^ (rb & 7);
                bfr[j] = *(const s16x8*)&sB[buf][rb * GBK + pc * 8];
            }
            int ra0 = wm * 128 + lo;
            int pc0 = (kk * 4 + hi) ^ (ra0 & 7);
            s16x8 a_cur = *(const s16x8*)&sA[buf][ra0 * GBK + pc0 * 8];
            __builtin_amdgcn_s_setprio(1);
#pragma unroll
            for (int i = 0; i < 8; i++) {
                s16x8 a_nxt;
                if (i < 7) {
                    int ra = wm * 128 + (i + 1) * 16 + lo;
                    int pc = (kk * 4 + hi) ^ (ra & 7);
                    a_nxt = *(const s16x8*)&sA[buf][ra * GBK + pc * 8];
                }
#pragma unroll
                for (int j = 0; j < 4; j++)
                    acc[i][j] = mfma16(a_cur, bfr[j], acc[i][j]);
                if (i < 7) a_cur = a_nxt;
            }
            __builtin_amdgcn_s_setprio(0);
        }
        __builtin_amdgcn_s_barrier();          // protect buf reuse next iter
    }

#pragma unroll
    for (int i = 0; i < 8; i++)
#pragma unroll
        for (int r = 0; r < 4; r++) {
            int m = m0 + wm * 128 + i * 16 + hi * 4 + r;
#pragma unroll
            for (int j = 0; j < 4; j++) {
                int n = n0 + wn * 64 + j * 16 + lo;
                float v = acc[i][j][r] + gb[n];
                gate[(size_t)m * DM + n] = 1.0f / (1.0f + __expf(-v));
            }
        }
}

// ---------------------------------------------------------------------------
// K3: windowed scan, register-prefetch bodies, NO LDS (R11-verified).
// Bx/Cx (pre-reduced) read via block-uniform addresses -> s_load broadcast.
// LOOKBACK 16: A <= e^-1 -> truncation ~1.2e-7 relative.
// ---------------------------------------------------------------------------
#define CHUNK_L 64
#define LOOKBACK 16

__global__ __launch_bounds__(256) void k_scan(
    const float* __restrict__ x, const float* __restrict__ A_log,
    const float* __restrict__ Bx, const float* __restrict__ Cx,
    const float* __restrict__ Dvec, float* gate_out)
{
    int d = blockIdx.x * 256 + threadIdx.x;   // 0..1023
    int b = blockIdx.z;
    int t0 = blockIdx.y * CHUNK_L;
    int tstart = t0 - LOOKBACK; if (tstart < 0) tstart = 0;
    int lb = t0 - tstart;                     // 0 or 16
    int T  = lb + CHUNK_L;                    // 64 or 80
    int NB = T >> 3;                          // 8 or 10 bodies (even)

    float A[DSTATE], h[DSTATE];
    const f32x4* ga = (const f32x4*)(A_log + (size_t)d * DSTATE);
#pragma unroll
    for (int q = 0; q < 4; q++) {
        f32x4 av = ga[q];
#pragma unroll
        for (int c = 0; c < 4; c++) {
            A[q * 4 + c] = expf(av[c]);
            h[q * 4 + c] = 0.0f;
        }
    }
    float Dd = Dvec[d];

    const float* xp = x + ((size_t)b * SEQ + tstart) * DM + d;
    float* gp = gate_out + ((size_t)b * SEQ + t0) * DM + d;
    // block-uniform row bases (scalarizable)
    const f32x4* bA = (const f32x4*)(Bx + ((size_t)b * SEQ + tstart) * DSTATE);
    const f32x4* cA = (const f32x4*)(Cx + ((size_t)b * SEQ + tstart) * DSTATE);

    auto pf = [&](int bd, float (&xr)[8], float (&gr)[8]) {
        int base = bd * 8;
#pragma unroll
        for (int q = 0; q < 8; q++) xr[q] = xp[(size_t)(base + q) * DM];
        if (base >= lb) {
#pragma unroll
            for (int q = 0; q < 8; q++) gr[q] = gp[(size_t)(base + q - lb) * DM];
        }
    };

    auto body = [&](int bd, float (&xr)[8], float (&gr)[8]) {
        int base = bd * 8;
        if (base >= lb) {
            float* go = gp + (size_t)(base - lb) * DM;
#pragma unroll
            for (int q = 0; q < 8; q++) {
                int idx = base + q;
                float xv = xr[q], gv = gr[q];
                f32x4 vb0 = bA[idx * 4 + 0], vb1 = bA[idx * 4 + 1];
                f32x4 vb2 = bA[idx * 4 + 2], vb3 = bA[idx * 4 + 3];
                f32x4 vc0 = cA[idx * 4 + 0], vc1 = cA[idx * 4 + 1];
                f32x4 vc2 = cA[idx * 4 + 2], vc3 = cA[idx * 4 + 3];
                float y0 = 0.f, y1 = 0.f, y2 = 0.f, y3 = 0.f;
#pragma unroll
                for (int c = 0; c < 4; c++) {
                    h[c]      = h[c]      * A[c]      + vb0[c] * xv;  y0 += h[c]      * vc0[c];
                    h[4 + c]  = h[4 + c]  * A[4 + c]  + vb1[c] * xv;  y1 += h[4 + c]  * vc1[c];
                    h[8 + c]  = h[8 + c]  * A[8 + c]  + vb2[c] * xv;  y2 += h[8 + c]  * vc2[c];
                    h[12 + c] = h[12 + c] * A[12 + c] + vb3[c] * xv;  y3 += h[12 + c] * vc3[c];
                }
                float yv = ((y0 + y1) + (y2 + y3)) + Dd * xv;
                go[(size_t)q * DM] = gv * yv + (1.0f - gv) * xv;
            }
        } else {
#pragma unroll
            for (int q = 0; q < 8; q++) {
                int idx = base + q;
                float xv = xr[q];
                f32x4 vb0 = bA[idx * 4 + 0], vb1 = bA[idx * 4 + 1];
                f32x4 vb2 = bA[idx * 4 + 2], vb3 = bA[idx * 4 + 3];
#pragma unroll
                for (int c = 0; c < 4; c++) {
                    h[c]      = h[c]      * A[c]      + vb0[c] * xv;
                    h[4 + c]  = h[4 + c]  * A[4 + c]  + vb1[c] * xv;
                    h[8 + c]  = h[8 + c]  * A[8 + c]  + vb2[c] * xv;
                    h[12 + c] = h[12 + c] * A[12 + c] + vb3[c] * xv;
                }
            }
        }
    };

    float xA[8], gA[8], xB[8], gB8[8];
    pf(0, xA, gA);
    for (int bd = 0; bd < NB; bd += 2) {
        pf(bd + 1, xB, gB8);          // issue next body's loads before compute
        body(bd, xA, gA);
        if (bd + 2 < NB) pf(bd + 2, xA, gA);
        body(bd + 1, xB, gB8);
    }
}

// ---------------------------------------------------------------------------
// K4: LayerNorm over last dim (1024), fp32, IN PLACE on d_out.
// ---------------------------------------------------------------------------
__global__ __launch_bounds__(256) void k_ln(
    float* data, const float* __restrict__ gamma, const float* __restrict__ beta)
{
    int wv = threadIdx.x >> 6, lane = threadIdx.x & 63;
    int row = blockIdx.x * 4 + wv;
    f32x4* rp = (f32x4*)(data + (size_t)row * DM);
    f32x4 v[4];
#pragma unroll
    for (int j = 0; j < 4; j++) v[j] = rp[lane + 64 * j];
    float s = 0.0f, s2 = 0.0f;
#pragma unroll
    for (int j = 0; j < 4; j++)
#pragma unroll
        for (int c = 0; c < 4; c++) { float t = v[j][c]; s += t; s2 += t * t; }
#pragma unroll
    for (int off = 32; off > 0; off >>= 1) {
        s  += __shfl_down(s,  off);
        s2 += __shfl_down(s2, off);
    }
    s = __shfl(s, 0); s2 = __shfl(s2, 0);
    float mu  = s  * (1.0f / DM);
    float var = s2 * (1.0f / DM) - mu * mu;
    float rs  = rsqrtf(var + 1e-5f);
#pragma unroll
    for (int j = 0; j < 4; j++) {
        int c0 = (lane + 64 * j) * 4;
        f32x4 o;
#pragma unroll
        for (int c = 0; c < 4; c++)
            o[c] = (v[j][c] - mu) * rs * gamma[c0 + c] + beta[c0 + c];
        rp[lane + 64 * j] = o;
    }
}

// ---------------------------------------------------------------------------
extern "C" void kernel_launch(void* const* d_in, const int* in_sizes, int n_in,
                              void* d_out, int out_size, void* d_ws, size_t ws_size,
                              hipStream_t stream)
{
    const float* x     = (const float*)d_in[0];
    const float* A_log = (const float*)d_in[1];
    const float* Bw    = (const float*)d_in[2];
    const float* Cw    = (const float*)d_in[3];
    const float* Dv    = (const float*)d_in[4];
    const float* gw    = (const float*)d_in[5];
    const float* gb    = (const float*)d_in[6];
    const float* gam   = (const float*)d_in[7];
    const float* bet   = (const float*)d_in[8];
    float* out = (float*)d_out;   // reused: gate (fp32) -> out_pre -> final

    char* ws = (char*)d_ws;
    u16*   xh  = (u16*)  ws;                             // 32 MB
    float* BxP = (float*)(ws + (32u << 20));             // 4 MB (4 slabs)
    float* CxP = (float*)(ws + (36u << 20));             // 4 MB (4 slabs)
    float* BxR = (float*)(ws + (40u << 20));             // 1 MB (reduced)
    float* CxR = (float*)(ws + (41u << 20));             // 1 MB (reduced)
    u16*   gwb = (u16*)  (ws + (64u << 20));             // 2 MB
    u16*   bwh = (u16*)  (ws + (66u << 20));             // 32 KB
    u16*   bwl = (u16*)  (ws + (66u << 20) + (32u << 10));
    u16*   cwh = (u16*)  (ws + (66u << 20) + (64u << 10));
    u16*   cwl = (u16*)  (ws + (66u << 20) + (96u << 10));

    k_cvt_w<<<1056, 256, 0, stream>>>(gw, Bw, Cw, gwb, bwh, bwl, cwh, cwl);
    k_bxcx<<<dim3(ROWS / 64, XKS), 256, 0, stream>>>(
        x, bwh, bwl, cwh, cwl, xh, BxP, CxP);
    k_red<<<SLAB_V4 / 256, 256, 0, stream>>>(BxP, CxP, BxR, CxR);
    k_gate<<<dim3(ROWS / GBM, DM / GBN), 512, 0, stream>>>(xh, gwb, gb, out);
    k_scan<<<dim3(DM / 256, SEQ / CHUNK_L, B_SZ), 256, 0, stream>>>(
        x, A_log, BxR, CxR, Dv, out);
    k_ln<<<ROWS / 4, 256, 0, stream>>>(out, gam, bet);
}